// Round 1
// baseline (873.606 us; speedup 1.0000x reference)
//
#include <hip/hip_runtime.h>

// IIR recurrence along time axis:
//   y[0] = x[0];  y[i] = W*x[i] + (1-W)*y[i-1]
// Shape (bs=4, c=8, n=64, h=256, w=256) fp32, recurrence on n (axis 2).
// Stride along n is h*w = 65536 floats; each (bs,c,h,w) position is an
// independent serial chain -> one thread per float4 of the h*w plane.
// Memory-bound: 512 MiB read + 512 MiB write, roofline ~170 us @ 6.3 TB/s.

#define N_TIME   64
#define PLANE    65536      // 256*256 floats, contiguous
#define PLANE_V4 16384      // PLANE / 4, float4 stride between time steps
#define N_SLABS  32         // bs*c = 4*8 independent (bs,c) slabs

__global__ __launch_bounds__(256) void
RecursiveFilter_63909113364758_kernel(const float* __restrict__ x,
                                      float* __restrict__ y) {
    const float W   = 0.8f;
    const float OMW = 1.0f - W;   // constant-folds to 0.19999999f, matching JAX's f32 (1.0 - w)

    const int tid    = blockIdx.x * blockDim.x + threadIdx.x;  // 0 .. 524287
    const int slab   = tid >> 14;          // / PLANE_V4  -> which (bs,c) slab
    const int within = tid & (PLANE_V4-1); // float4 index inside the h*w plane

    const size_t base = (size_t)slab * ((size_t)N_TIME * PLANE) + (size_t)within * 4;
    const float4* __restrict__ xp = (const float4*)(x + base);
    float4* __restrict__       yp = (float4*)(y + base);

    float4 carry = xp[0];
    yp[0] = carry;

    #pragma unroll 4
    for (int i = 1; i < N_TIME; ++i) {
        float4 xi = xp[(size_t)i * PLANE_V4];
        carry.x = W * xi.x + OMW * carry.x;
        carry.y = W * xi.y + OMW * carry.y;
        carry.z = W * xi.z + OMW * carry.z;
        carry.w = W * xi.w + OMW * carry.w;
        yp[(size_t)i * PLANE_V4] = carry;
    }
}

extern "C" void kernel_launch(void* const* d_in, const int* in_sizes, int n_in,
                              void* d_out, int out_size, void* d_ws, size_t ws_size,
                              hipStream_t stream) {
    const float* x = (const float*)d_in[0];
    float*       y = (float*)d_out;

    // 32 slabs * 16384 float4-chains = 524288 threads
    const int total_threads = N_SLABS * PLANE_V4;
    const int block = 256;
    const int grid  = total_threads / block;   // 2048 blocks = 8 per CU

    RecursiveFilter_63909113364758_kernel<<<grid, block, 0, stream>>>(x, y);
}